// Round 6
// baseline (289.924 us; speedup 1.0000x reference)
//
#include <hip/hip_runtime.h>

#define IMG  512
#define BTX  64            // block threads x
#define BTY  4             // block threads y
#define PXY  2             // pixels per thread in y
#define TW   128           // tile width  = BTX * 2
#define TH   8             // tile height = BTY * PXY
#define HALO 2
#define LWD  (TW + 4)      // 132 data cols
#define LW   136           // padded row stride (even -> b64-aligned)
#define LH   (TH + 4)      // 12 rows -> LDS = 12*136*4 = 6528 B

typedef float v2f __attribute__((ext_vector_type(2)));
typedef int   v2i __attribute__((ext_vector_type(2)));

// q = p * KS2, KS2 = sqrt(50/ln2) * 2^11.5 : intensity term directly in
// float exponent-field units (Schraudolph exp2, validated rounds 4-5,
// absmax 0.0039 vs threshold 0.02).
#define KS2      24598.990f
#define INV_KS2  4.0652061e-05f

__device__ __forceinline__ int reflect_idx(int g) {
    int a = abs(g);
    return min(a, 2 * IMG - 2 - a);
}

// min 8 waves/EU -> VGPR capped at 64; LDS 6.5KB -> residency not LDS-starved
__global__ __launch_bounds__(256, 8) void bilateral_kernel(
    const float* __restrict__ img, float* __restrict__ out)
{
    __shared__ float q[LH][LW];

    const int plane = blockIdx.z;
    const int x0 = blockIdx.x * TW;
    const int y0 = blockIdx.y * TH;
    const float* __restrict__ src = img + (size_t)plane * (IMG * IMG);

    const int tx = threadIdx.x, ty = threadIdx.y;

    // Stage 12 rows x 132 cols, division-free: pass p covers row 4*p + ty.
    #pragma unroll
    for (int p = 0; p < 3; ++p) {
        int r  = 4 * p + ty;
        int gr = reflect_idx(y0 - HALO + r) * IMG;
        q[r][tx]      = src[gr + reflect_idx(x0 - HALO + tx)]      * KS2;
        q[r][tx + 64] = src[gr + reflect_idx(x0 - HALO + tx + 64)] * KS2;
        if (tx < 4)
            q[r][tx + 128] = src[gr + reflect_idx(x0 - HALO + tx + 128)] * KS2;
    }
    __syncthreads();

    // Batched window load: 6 rows x 6 cols into registers (18x ds_read_b64).
    // ty uniform per wave -> each read is 512B contiguous, conflict-free.
    float w[PXY + 4][6];
    #pragma unroll
    for (int r = 0; r < PXY + 4; ++r) {
        const float* row = &q[PXY * ty + r][2 * tx];
        v2f a = *reinterpret_cast<const v2f*>(row);
        v2f b = *reinterpret_cast<const v2f*>(row + 2);
        v2f c = *reinterpret_cast<const v2f*>(row + 4);
        w[r][0] = a.x; w[r][1] = a.y;
        w[r][2] = b.x; w[r][3] = b.y;
        w[r][4] = c.x; w[r][5] = c.y;
    }

    v2f res[PXY];
    #pragma unroll
    for (int p = 0; p < PXY; ++p) {
        v2f qc;
        qc.x = w[p + 2][2];
        qc.y = w[p + 2][3];
        v2f wsum = {1.0f, 1.0f};   // center tap exact
        v2f acc  = qc;

        #pragma unroll
        for (int dy = 0; dy < 5; ++dy) {
            #pragma unroll
            for (int dx = 0; dx < 5; ++dx) {
                if (dx == 2 && dy == 2) continue;
                const int r2 = (dx - 2) * (dx - 2) + (dy - 2) * (dy - 2);
                // Ktap = float_bias + 2^23*log2(spatial_w), exponent units
                const float Ktap = (float)(1065353216.0 - 6051101.63118 * (double)r2);

                v2f qt;
                qt.x = w[p + dy][dx];
                qt.y = w[p + dy][dx + 1];

                v2f d = qt - qc;                          // pk sub
                v2f t = Ktap - d * d;                     // pk fma
                v2i iv = __builtin_convertvector(t, v2i); // 2x v_cvt_i32_f32
                v2f e  = __builtin_bit_cast(v2f, iv);     // e ~ 2^arg

                wsum += e;
                acc  += e * qt;
            }
        }
        res[p].x = acc.x * __builtin_amdgcn_rcpf(wsum.x) * INV_KS2;
        res[p].y = acc.y * __builtin_amdgcn_rcpf(wsum.y) * INV_KS2;
    }

    float* dst = out + (size_t)plane * (IMG * IMG)
                     + (size_t)(y0 + PXY * ty) * IMG + (x0 + 2 * tx);
    #pragma unroll
    for (int p = 0; p < PXY; ++p)
        *reinterpret_cast<v2f*>(dst + p * IMG) = res[p];
}

extern "C" void kernel_launch(void* const* d_in, const int* in_sizes, int n_in,
                              void* d_out, int out_size, void* d_ws, size_t ws_size,
                              hipStream_t stream) {
    const float* img = (const float*)d_in[0];
    float* out = (float*)d_out;
    int planes = in_sizes[0] / (IMG * IMG);  // 48
    dim3 grid(IMG / TW, IMG / TH, planes);   // (4, 64, 48)
    dim3 block(BTX, BTY, 1);
    bilateral_kernel<<<grid, block, 0, stream>>>(img, out);
}

// Round 7
// 128.622 us; speedup vs baseline: 2.2541x; 2.2541x over previous
//
#include <hip/hip_runtime.h>
#include <stdint.h>

#define IMG  512
#define BTX  64            // block threads x
#define BTY  4             // block threads y
#define PXY  2             // pixel rows per thread
#define TW   128           // tile width  = BTX * 2
#define TH   8             // tile height = BTY * PXY
#define HALO 2
#define LWD  (TW + 4)      // 132 data cols
#define LW   136           // padded row stride (even -> b64-aligned)
#define LH   (TH + 4)      // 12 rows -> LDS = 12*136*4 = 6528 B

typedef float v2f __attribute__((ext_vector_type(2)));
typedef int   v2i __attribute__((ext_vector_type(2)));

// q = p * KS2, KS2 = sqrt(50/ln2) * 2^11.5 : intensity term directly in
// float exponent-field units (Schraudolph exp2; absmax 0.0039 vs thr 0.02,
// validated rounds 4-6).
#define KS2      24598.990f
#define INV_KS2  4.0652061e-05f

__device__ __forceinline__ int reflect_idx(int g) {
    int a = abs(g);
    return min(a, 2 * IMG - 2 - a);
}

// (256,4): VGPR cap 128 — room for the 36-reg window, NO spill (R6 lesson:
// the (256,8)/64-cap forced scratch spill -> 565MB HBM writes, 216us).
__global__ __launch_bounds__(256, 4) void bilateral_kernel(
    const float* __restrict__ img, float* __restrict__ out)
{
    __shared__ float q[LH][LW];

    const int plane = blockIdx.z;
    const int x0 = blockIdx.x * TW;
    const int y0 = blockIdx.y * TH;
    const float* __restrict__ src = img + (size_t)plane * (IMG * IMG);

    const int tx = threadIdx.x, ty = threadIdx.y;

    // Stage 12 rows x 132 cols, division-free: pass p covers row 4*p + ty.
    #pragma unroll
    for (int p = 0; p < 3; ++p) {
        int r  = 4 * p + ty;
        int gr = reflect_idx(y0 - HALO + r) * IMG;
        q[r][tx]      = src[gr + reflect_idx(x0 - HALO + tx)]      * KS2;
        q[r][tx + 64] = src[gr + reflect_idx(x0 - HALO + tx + 64)] * KS2;
        if (tx < 4)
            q[r][tx + 128] = src[gr + reflect_idx(x0 - HALO + tx + 128)] * KS2;
    }
    __syncthreads();

    // Batched window: 6 rows x 6 cols into registers (18x ds_read_b64).
    // ty uniform per wave -> 512B contiguous per read, conflict-free (R5/R6: 0).
    float w[PXY + 4][6];
    #pragma unroll
    for (int r = 0; r < PXY + 4; ++r) {
        const float* row = &q[PXY * ty + r][2 * tx];
        v2f a = *reinterpret_cast<const v2f*>(row);
        v2f b = *reinterpret_cast<const v2f*>(row + 2);
        v2f c = *reinterpret_cast<const v2f*>(row + 4);
        w[r][0] = a.x; w[r][1] = a.y;
        w[r][2] = b.x; w[r][3] = b.y;
        w[r][4] = c.x; w[r][5] = c.y;
    }

    v2f res[PXY];
    #pragma unroll
    for (int p = 0; p < PXY; ++p) {
        v2f qc;
        qc.x = w[p + 2][2];
        qc.y = w[p + 2][3];
        v2f wsum = {1.0f, 1.0f};   // center tap exact
        v2f acc  = qc;

        #pragma unroll
        for (int dy = 0; dy < 5; ++dy) {
            #pragma unroll
            for (int dx = 0; dx < 5; ++dx) {
                if (dx == 2 && dy == 2) continue;
                const int r2 = (dx - 2) * (dx - 2) + (dy - 2) * (dy - 2);
                // Ktap = float_bias + 2^23*log2(spatial_w), exponent units;
                // broadcast into both halves of an SGPR pair (1 sgpr read ok).
                const float    Kf    = (float)(1065353216.0 - 6051101.63118 * (double)r2);
                const uint32_t kb    = __builtin_bit_cast(uint32_t, Kf);
                const uint64_t kpair = ((uint64_t)kb << 32) | kb;

                v2f qt;
                qt.x = w[p + dy][dx];
                qt.y = w[p + dy][dx + 1];

                v2f d, t;
                // d = qt - qc
                asm("v_pk_add_f32 %0, %1, %2 neg_lo:[0,1] neg_hi:[0,1]"
                    : "=v"(d) : "v"(qt), "v"(qc));
                // t = K - d*d
                asm("v_pk_fma_f32 %0, %1, %1, %2 neg_lo:[1,0,0] neg_hi:[1,0,0]"
                    : "=v"(t) : "v"(d), "s"(kpair));

                v2i iv = __builtin_convertvector(t, v2i);  // 2x v_cvt_i32_f32
                v2f e  = __builtin_bit_cast(v2f, iv);      // e ~ 2^arg (free)

                // wsum += e ; acc += e*qt
                asm("v_pk_add_f32 %0, %1, %0" : "+v"(wsum) : "v"(e));
                asm("v_pk_fma_f32 %0, %1, %2, %0" : "+v"(acc) : "v"(e), "v"(qt));
            }
        }
        res[p].x = acc.x * __builtin_amdgcn_rcpf(wsum.x) * INV_KS2;
        res[p].y = acc.y * __builtin_amdgcn_rcpf(wsum.y) * INV_KS2;
    }

    float* dst = out + (size_t)plane * (IMG * IMG)
                     + (size_t)(y0 + PXY * ty) * IMG + (x0 + 2 * tx);
    #pragma unroll
    for (int p = 0; p < PXY; ++p)
        *reinterpret_cast<v2f*>(dst + p * IMG) = res[p];
}

extern "C" void kernel_launch(void* const* d_in, const int* in_sizes, int n_in,
                              void* d_out, int out_size, void* d_ws, size_t ws_size,
                              hipStream_t stream) {
    const float* img = (const float*)d_in[0];
    float* out = (float*)d_out;
    int planes = in_sizes[0] / (IMG * IMG);  // 48
    dim3 grid(IMG / TW, IMG / TH, planes);   // (4, 64, 48)
    dim3 block(BTX, BTY, 1);
    bilateral_kernel<<<grid, block, 0, stream>>>(img, out);
}